// Round 1
// baseline (612.664 us; speedup 1.0000x reference)
//
#include <hip/hip_runtime.h>

// Problem: MyStrategicModel_35691178229867
// R9 theory: VALU-bound (VALUBusy 85%) but Occupancy 30% vs 50% static =>
// wave lifetimes vary ~40%. Cause: CCP early-exit is wave-__all gated, so
// each wave runs ~p98 of its 128 samples' round counts. Restructure into
// 11 per-round dispatches + 1 final dispatch with per-PAIR convergence
// compaction via workspace queues. Exit test is the same exact bitwise
// fc-periodicity (per1 => xt frozen; per2+parity => xt_11 == xt_c), so the
// math is bitwise-identical to the monolithic kernel -- absmax must stay
// exactly 0.015625. solve() is byte-identical to R8.
// Predict: dur 191 -> ~125-155 us; WRITE_SIZE up ~tens of MB (state).

#define XLO -10.0f
#define XHI 10.0f

typedef float v2 __attribute__((ext_vector_type(2)));

__device__ __forceinline__ v2 fma2(v2 a, v2 b, v2 c) {
    return __builtin_elementwise_fma(a, b, c);
}

__device__ __forceinline__ float clampx(float x) {
    return fminf(fmaxf(x, XLO), XHI);   // v_med3_f32
}

__device__ __forceinline__ v2 clamp2(v2 x) {
    v2 r;
    r.x = clampx(x.x);
    r.y = clampx(x.y);
    return r;
}

__device__ __forceinline__ float rsq_nr(float t) {
    float y = __builtin_amdgcn_rsqf(t);
    float c = __builtin_fmaf(-0.5f * (t * y), y, 1.5f);
    return y * c;
}

struct P {
    v2 w0s, w1s, v0s, v1s, bm1s, hw0s, hw1s, mvr;
};

// nblocks blocks of 4 PGA steps; gc refreshed per block, folded into the
// kink-branch constants f*/f*k. Kink test + clip exact per step.
// (byte-identical to R8)
__device__ __forceinline__ void solve(int nblocks, v2 sx0, v2 sx1,
                                      v2 e0, v2 e1, v2 e0k, v2 e1k,
                                      const P& p, v2& ox0, v2& ox1) {
    const v2 c95 = 0.95f, one = 1.0f;
    v2 x0 = sx0, x1 = sx1;
    for (int k = 0; k < nblocks; ++k) {
        v2 tau = fma2(x0, p.w0s, fma2(x1, p.w1s, p.bm1s));
        v2 t2 = fma2(tau, tau, one);
        v2 rq;
        rq.x = __builtin_amdgcn_rsqf(t2.x);
        rq.y = __builtin_amdgcn_rsqf(t2.y);
        v2 gc = tau * rq;
        v2 f0  = fma2(-gc, p.hw0s, e0);    // no-kink branch const, gc folded
        v2 f0k = fma2(-gc, p.hw0s, e0k);   // kink branch const
        v2 f1  = fma2(-gc, p.hw1s, e1);
        v2 f1k = fma2(-gc, p.hw1s, e1k);
#pragma unroll
        for (int h = 0; h < 4; ++h) {
            v2 q = fma2(x0, p.v0s, fma2(x1, p.v1s, p.mvr));
            v2 a0, a1;
            a0.x = (q.x > 0.0f) ? f0k.x : f0.x;
            a0.y = (q.y > 0.0f) ? f0k.y : f0.y;
            a1.x = (q.x > 0.0f) ? f1k.x : f1.x;
            a1.y = (q.y > 0.0f) ? f1k.y : f1.y;
            x0 = clamp2(fma2(c95, x0, a0));
            x1 = clamp2(fma2(c95, x1, a1));
        }
    }
    ox0 = x0;
    ox1 = x1;
}

// Per-pair constants, identical expressions/order to the monolithic kernel.
struct C2 {
    P p;
    v2 sx0, sx1, p5r0, p5r1, bp1s, k0s, k1s;
};

__device__ __forceinline__ void build_consts(float4 r4, float w0, float w1,
                                             float b, float v0, float v1,
                                             C2& c, v2& r0, v2& r1) {
    c.p.w0s = w0; c.p.w1s = w1; c.p.v0s = v0; c.p.v1s = v1;
    c.p.bm1s = b - 1.0f;
    c.p.hw0s = 0.5f * w0; c.p.hw1s = 0.5f * w1;
    c.bp1s = b + 1.0f;
    c.k0s = 0.475f * v0;
    c.k1s = 0.475f * v1;
    const v2 c05 = 0.05f;

    r0.x = r4.x; r0.y = r4.z;   // coord 0 of both samples
    r1.x = r4.y; r1.y = r4.w;   // coord 1 of both samples

    c.sx0 = clamp2(r0); c.sx1 = clamp2(r1);
    c.p.mvr.x = -(__builtin_fmaf(r1.x, v1, r0.x * v0));
    c.p.mvr.y = -(__builtin_fmaf(r1.y, v1, r0.y * v0));
    c.p5r0 = c05 * r0; c.p5r1 = c05 * r1;
}

// fder + e-constants; identical expression order to the monolithic kernel.
__device__ __forceinline__ void fder_e(const C2& cc, v2 xt0, v2 xt1,
                                       v2& fc, v2& e0, v2& e1, v2& e0k, v2& e1k) {
    const v2 one = 1.0f, half = 0.5f;
    v2 sp = fma2(xt0, cc.p.w0s, fma2(xt1, cc.p.w1s, cc.bp1s));
    v2 tt = fma2(sp, sp, one);
    v2 rs;
    rs.x = rsq_nr(tt.x);
    rs.y = rsq_nr(tt.y);
    fc = half * sp * rs;
    e0 = fma2(fc, cc.p.w0s, cc.p5r0);
    e1 = fma2(fc, cc.p.w1s, cc.p5r1);
    e0k = e0 - cc.k0s;
    e1k = e1 - cc.k1s;
}

// ---------------- Split path: one CCP round per dispatch ----------------

__global__ __launch_bounds__(256, 8)
void ccp_round(const float* __restrict__ X,
               const float* __restrict__ wp,
               const float* __restrict__ bp,
               const float* __restrict__ vp,
               float4* __restrict__ xt_buf,
               float2* __restrict__ fc1_buf,
               float2* __restrict__ fc2_buf,
               int* __restrict__ cnts,
               unsigned* __restrict__ idxA,
               unsigned* __restrict__ idxB,
               int B2, int c) {
    int p = blockIdx.x * blockDim.x + threadIdx.x;
    int active = (c == 0) ? B2 : cnts[c];
    if (p >= active) return;
    unsigned id = (c == 0) ? (unsigned)p : ((c & 1) ? idxA[p] : idxB[p]);

    const float w0 = wp[0], w1 = wp[1], b = bp[0], v0 = vp[0], v1 = vp[1];
    float4 r4 = reinterpret_cast<const float4*>(X)[id];
    C2 cc; v2 r0, r1;
    build_consts(r4, w0, w1, b, v0, v1, cc, r0, r1);

    v2 xt0, xt1;
    if (c == 0) {
        xt0 = r0; xt1 = r1;
    } else {
        float4 x4 = xt_buf[id];
        xt0.x = x4.x; xt0.y = x4.y; xt1.x = x4.z; xt1.y = x4.w;
    }

    v2 fc, e0, e1, e0k, e1k;
    fder_e(cc, xt0, xt1, fc, e0, e1, e0k, e1k);

    float2 f1old;
    if (c > 0) {
        f1old = fc1_buf[id];
        float2 f2old = fc2_buf[id];
        int par = (10 - c) & 1;
        // per-sample exact exit: per1 => xt frozen; per2 needs parity match
        bool exA = (fc.x == f1old.x) || ((fc.x == f2old.x) && par);
        bool exB = (fc.y == f1old.y) || ((fc.y == f2old.y) && par);
        if (exA && exB) return;   // xt_buf[id] already holds the final xt
    }

    solve(25, cc.sx0, cc.sx1, e0, e1, e0k, e1k, cc.p, xt0, xt1);  // 100 steps

    float4 xw;
    xw.x = xt0.x; xw.y = xt0.y; xw.z = xt1.x; xw.w = xt1.y;
    xt_buf[id] = xw;

    if (c < 10) {
        int pos = atomicAdd(&cnts[c + 1], 1);
        ((c & 1) ? idxB : idxA)[pos] = id;    // round c writes queue for c+1
        float2 w2;
        if (c == 0) {
            w2.x = __builtin_nanf("");        // NaN never compares equal
            w2.y = w2.x;
        } else {
            w2 = f1old;                       // fc_p2 = fc_p1
        }
        fc2_buf[id] = w2;
        float2 w1f;
        w1f.x = fc.x; w1f.y = fc.y;           // fc_p1 = fc
        fc1_buf[id] = w1f;
    }
}

__global__ __launch_bounds__(256, 8)
void final_solve_k(const float* __restrict__ X,
                   const float* __restrict__ wp,
                   const float* __restrict__ bp,
                   const float* __restrict__ vp,
                   const float4* __restrict__ xt_buf,
                   float* __restrict__ out, int B2) {
    int p = blockIdx.x * blockDim.x + threadIdx.x;
    if (p >= B2) return;

    const float w0 = wp[0], w1 = wp[1], b = bp[0], v0 = vp[0], v1 = vp[1];
    float4 r4 = reinterpret_cast<const float4*>(X)[p];
    C2 cc; v2 r0, r1;
    build_consts(r4, w0, w1, b, v0, v1, cc, r0, r1);

    float4 x4 = xt_buf[p];
    v2 xt0, xt1;
    xt0.x = x4.x; xt0.y = x4.y; xt1.x = x4.z; xt1.y = x4.w;

    // e = fd(xt_final): bitwise-identical to both the break path and the
    // c==11 refresh path of the monolithic kernel.
    v2 fc, e0, e1, e0k, e1k;
    fder_e(cc, xt0, xt1, fc, e0, e1, e0k, e1k);

    // Final (differentiable) solve: 200 steps = 50 blocks
    v2 x0, x1;
    solve(50, cc.sx0, cc.sx1, e0, e1, e0k, e1k, cc.p, x0, x1);

    v2 bs = b;
    v2 res = fma2(x0, cc.p.w0s, fma2(x1, cc.p.w1s, bs));
    float2 o;
    o.x = res.x;
    o.y = res.y;
    reinterpret_cast<float2*>(out)[p] = o;
}

// ---------------- Fallback: R8 monolithic kernel (unchanged) ----------------

__global__ __launch_bounds__(256, 8)
void strategic_kernel(const float* __restrict__ X,
                      const float* __restrict__ wp,
                      const float* __restrict__ bp,
                      const float* __restrict__ vp,
                      float* __restrict__ out, int B2) {
    int i = blockIdx.x * blockDim.x + threadIdx.x;
    if (i >= B2) return;

    const float w0 = wp[0], w1 = wp[1], b = bp[0], v0 = vp[0], v1 = vp[1];

    float4 r4 = reinterpret_cast<const float4*>(X)[i];
    C2 cc; v2 r0, r1;
    build_consts(r4, w0, w1, b, v0, v1, cc, r0, r1);

    v2 xt0 = r0, xt1 = r1;
    v2 fc_p1 = __builtin_nanf(""), fc_p2 = __builtin_nanf("");
    v2 fc, e0, e1, e0k, e1k;

    int c = 0;
    for (; c < 11; ++c) {
        fder_e(cc, xt0, xt1, fc, e0, e1, e0k, e1k);
        bool per1 = (fc.x == fc_p1.x) && (fc.y == fc_p1.y);
        bool per2 = (fc.x == fc_p2.x) && (fc.y == fc_p2.y);
        if (__all(per1) || (__all(per2) && ((10 - c) & 1))) break;
        fc_p2 = fc_p1;
        fc_p1 = fc;
        solve(25, cc.sx0, cc.sx1, e0, e1, e0k, e1k, cc.p, xt0, xt1);
    }
    if (c == 11) {
        fder_e(cc, xt0, xt1, fc, e0, e1, e0k, e1k);
    }

    v2 x0, x1;
    solve(50, cc.sx0, cc.sx1, e0, e1, e0k, e1k, cc.p, x0, x1);

    v2 bs = b;
    v2 res = fma2(x0, cc.p.w0s, fma2(x1, cc.p.w1s, bs));
    float2 o;
    o.x = res.x;
    o.y = res.y;
    reinterpret_cast<float2*>(out)[i] = o;
}

extern "C" void kernel_launch(void* const* d_in, const int* in_sizes, int n_in,
                              void* d_out, int out_size, void* d_ws, size_t ws_size,
                              hipStream_t stream) {
    const float* X = (const float*)d_in[0];
    const float* w = (const float*)d_in[1];
    const float* b = (const float*)d_in[2];
    const float* v = (const float*)d_in[3];
    float* out = (float*)d_out;

    int B = in_sizes[0] / 2;   // X is [B, 2]
    int B2 = B / 2;            // 2 samples per thread (packed pairs)
    int block = 256;
    int grid = (B2 + block - 1) / block;

    // Workspace: cnts(256B) | xt(16B*B2) | fc1(8B*B2) | fc2(8B*B2)
    //            | idxA(4B*B2) | idxB(4B*B2)
    size_t need = 256 + (size_t)B2 * 40;
    if (d_ws != nullptr && ws_size >= need) {
        char* wsp = (char*)d_ws;
        int*      cnts = (int*)wsp;
        float4*   xt   = (float4*)(wsp + 256);
        float2*   fc1  = (float2*)(wsp + 256 + (size_t)B2 * 16);
        float2*   fc2  = (float2*)(wsp + 256 + (size_t)B2 * 24);
        unsigned* idxA = (unsigned*)(wsp + 256 + (size_t)B2 * 32);
        unsigned* idxB = (unsigned*)(wsp + 256 + (size_t)B2 * 36);

        hipMemsetAsync(cnts, 0, 64, stream);
        for (int c = 0; c <= 10; ++c) {
            ccp_round<<<grid, block, 0, stream>>>(X, w, b, v, xt, fc1, fc2,
                                                  cnts, idxA, idxB, B2, c);
        }
        final_solve_k<<<grid, block, 0, stream>>>(X, w, b, v, xt, out, B2);
    } else {
        strategic_kernel<<<grid, block, 0, stream>>>(X, w, b, v, out, B2);
    }
}

// Round 2
// 213.463 us; speedup vs baseline: 2.8701x; 2.8701x over previous
//
#include <hip/hip_runtime.h>

// Problem: MyStrategicModel_35691178229867
// R10: revert R9 split (FAILED 613us: compaction never shrinks -- WRITE_SIZE
// shows ~all pairs survive all 10 rounds; round kernels latency-bound at
// VALUBusy 18%). Back to monolithic, but UNPACK to 1 sample/thread:
//  - v_pk_f32 has no throughput edge on CDNA (2 pk = 4 scalar VALU cycles),
//    the v2 packing only halved the grid: 1024 blocks = 4 blk/CU = 50% static
//    occupancy cap. 1 sample/thread -> 2048 blocks = 8 blk/CU = 32 waves/CU.
//  - wave __all exit now spans 64 samples (was 128): fires >= as often;
//    exit conditions are per-sample exact (R9 passed bitwise), so output
//    is bit-identical regardless of wave grouping.
//  - clamp via __builtin_amdgcn_fmed3f (== fmin(fmax) for finite x).
// Per-sample op order identical to R8 => absmax must stay exactly 0.015625.
// Predict: dur 191 -> ~125-145 dispatch, VALUBusy 85 -> 92+%.

#define XLO -10.0f
#define XHI 10.0f

__device__ __forceinline__ float clampx(float x) {
    return __builtin_amdgcn_fmed3f(x, XLO, XHI);   // v_med3_f32, x finite
}

__device__ __forceinline__ float rsq_nr(float t) {
    float y = __builtin_amdgcn_rsqf(t);
    float c = __builtin_fmaf(-0.5f * (t * y), y, 1.5f);
    return y * c;
}

struct P {
    float w0, w1, v0, v1, bm1, hw0, hw1, mvr;
};

// nblocks blocks of 4 PGA steps; gc refreshed per block, folded into the
// kink-branch constants f*/f*k. Kink test + clip exact per step.
// Scalar transcription of R8's solve(): per-sample op order identical.
__device__ __forceinline__ void solve(int nblocks, float sx0, float sx1,
                                      float e0, float e1, float e0k, float e1k,
                                      const P& p, float& ox0, float& ox1) {
    float x0 = sx0, x1 = sx1;
    for (int k = 0; k < nblocks; ++k) {
        float tau = __builtin_fmaf(x0, p.w0, __builtin_fmaf(x1, p.w1, p.bm1));
        float t2  = __builtin_fmaf(tau, tau, 1.0f);
        float rq  = __builtin_amdgcn_rsqf(t2);
        float gc  = tau * rq;
        float f0  = __builtin_fmaf(-gc, p.hw0, e0);    // no-kink branch const
        float f0k = __builtin_fmaf(-gc, p.hw0, e0k);   // kink branch const
        float f1  = __builtin_fmaf(-gc, p.hw1, e1);
        float f1k = __builtin_fmaf(-gc, p.hw1, e1k);
#pragma unroll
        for (int h = 0; h < 4; ++h) {
            float q  = __builtin_fmaf(x0, p.v0, __builtin_fmaf(x1, p.v1, p.mvr));
            float a0 = (q > 0.0f) ? f0k : f0;
            float a1 = (q > 0.0f) ? f1k : f1;
            x0 = clampx(__builtin_fmaf(0.95f, x0, a0));
            x1 = clampx(__builtin_fmaf(0.95f, x1, a1));
        }
    }
    ox0 = x0;
    ox1 = x1;
}

__global__ __launch_bounds__(256, 8)
void strategic_kernel(const float* __restrict__ X,
                      const float* __restrict__ wp,
                      const float* __restrict__ bp,
                      const float* __restrict__ vp,
                      float* __restrict__ out, int B) {
    int i = blockIdx.x * blockDim.x + threadIdx.x;
    if (i >= B) return;

    const float w0 = wp[0], w1 = wp[1], b = bp[0], v0 = vp[0], v1 = vp[1];

    P p;
    p.w0 = w0; p.w1 = w1; p.v0 = v0; p.v1 = v1;
    p.bm1 = b - 1.0f;
    p.hw0 = 0.5f * w0; p.hw1 = 0.5f * w1;
    const float bp1 = b + 1.0f;
    const float k0 = 0.475f * v0, k1 = 0.475f * v1;   // COST*(1-EPS)*v

    float2 r = reinterpret_cast<const float2*>(X)[i];
    const float r0 = r.x, r1 = r.y;

    const float sx0 = clampx(r0), sx1 = clampx(r1);   // inner-solve start
    p.mvr = -(__builtin_fmaf(r1, v1, r0 * v0));
    const float p5r0 = 0.05f * r0, p5r1 = 0.05f * r1;
    float xt0 = r0, xt1 = r1;                         // CCP state

    // fc history for exact cycle detection (NaN never compares equal)
    float fc_p1 = __builtin_nanf(""), fc_p2 = __builtin_nanf("");
    float e0, e1, e0k, e1k;

    int c = 0;
    for (; c < 11; ++c) {
        // fder at xt (NR-refined rsq; 11 calls, cheap)
        float sp = __builtin_fmaf(xt0, p.w0, __builtin_fmaf(xt1, p.w1, bp1));
        float tt = __builtin_fmaf(sp, sp, 1.0f);
        float rs = rsq_nr(tt);
        float fc = (0.5f * sp) * rs;
        e0 = __builtin_fmaf(fc, p.w0, p5r0);
        e1 = __builtin_fmaf(fc, p.w1, p5r1);
        e0k = e0 - k0;
        e1k = e1 - k1;

        bool per1 = (fc == fc_p1);
        bool per2 = (fc == fc_p2);
        if (__all(per1) || (__all(per2) && ((10 - c) & 1))) break;
        fc_p2 = fc_p1;
        fc_p1 = fc;

        solve(25, sx0, sx1, e0, e1, e0k, e1k, p, xt0, xt1);  // 100 steps
    }

    if (c == 11) {   // natural exhaust: e-consts are fd(S_9); refresh at S_10
        float sp = __builtin_fmaf(xt0, p.w0, __builtin_fmaf(xt1, p.w1, bp1));
        float tt = __builtin_fmaf(sp, sp, 1.0f);
        float rs = rsq_nr(tt);
        float fc = (0.5f * sp) * rs;
        e0 = __builtin_fmaf(fc, p.w0, p5r0);
        e1 = __builtin_fmaf(fc, p.w1, p5r1);
        e0k = e0 - k0;
        e1k = e1 - k1;
    }

    // Final (differentiable) solve: 200 steps = 50 blocks
    float x0, x1;
    solve(50, sx0, sx1, e0, e1, e0k, e1k, p, x0, x1);

    out[i] = __builtin_fmaf(x0, p.w0, __builtin_fmaf(x1, p.w1, b));
}

extern "C" void kernel_launch(void* const* d_in, const int* in_sizes, int n_in,
                              void* d_out, int out_size, void* d_ws, size_t ws_size,
                              hipStream_t stream) {
    const float* X = (const float*)d_in[0];
    const float* w = (const float*)d_in[1];
    const float* b = (const float*)d_in[2];
    const float* v = (const float*)d_in[3];
    float* out = (float*)d_out;

    int B = in_sizes[0] / 2;   // X is [B, 2], 1 sample per thread
    int block = 256;
    int grid = (B + block - 1) / block;
    strategic_kernel<<<grid, block, 0, stream>>>(X, w, b, v, out, B);
}

// Round 4
// 148.485 us; speedup vs baseline: 4.1261x; 1.4376x over previous
//
#include <hip/hip_runtime.h>

// Problem: MyStrategicModel_35691178229867
// R12: revert R11's 10-step gc blocks (FAILED absmax 3.71: staleness ~1e-1
// bifurcates kink-branch flips for tail samples -- only bitwise-exact or
// <=4-step-staleness-scale perturbations are safe). Base = R10 (184us,
// absmax 0.015625, VALU-issue-bound, 14.9k insts/wave, occupancy at cap).
// Single change: CCP break gates go from exact bitwise fc equality (proven
// by R9 to ~never fire) to approximate |dfc| <= 2e-4 wave-uniform gates.
// Error bound vs reference TRAJECTORY (not limit): reference runs only
// (10-c) more rounds, so breaking at wave-max |dfc|<=tau deviates by
// <= tau*(10-c)*20*|w|^2 <= 0.04 < 0.11 margin, independent of the CCP
// contraction ratio (slow contraction => gate can't fire anyway).
// Period-2 handled by existing parity logic at same tolerance.
// Predict: if waves converge ~round 4-6: dispatch 184 -> 100-135us.
// If gate never fires: unchanged (falsifies convergence theory).
// absmax expected <= ~0.05 (0.13125 threshold).

#define XLO -10.0f
#define XHI 10.0f
#define TAU_CONV 2e-4f

__device__ __forceinline__ float clampx(float x) {
    return __builtin_amdgcn_fmed3f(x, XLO, XHI);   // v_med3_f32, x finite
}

__device__ __forceinline__ float rsq_nr(float t) {
    float y = __builtin_amdgcn_rsqf(t);
    float c = __builtin_fmaf(-0.5f * (t * y), y, 1.5f);
    return y * c;
}

struct P {
    float w0, w1, v0, v1, bm1, hw0, hw1, mvr;
};

// nblocks blocks of 4 PGA steps; gc refreshed per block, folded into the
// kink-branch constants f*/f*k. Kink test + clip exact per step.
// Byte-identical math to R10's solve().
__device__ __forceinline__ void solve(int nblocks, float sx0, float sx1,
                                      float e0, float e1, float e0k, float e1k,
                                      const P& p, float& ox0, float& ox1) {
    float x0 = sx0, x1 = sx1;
    for (int k = 0; k < nblocks; ++k) {
        float tau = __builtin_fmaf(x0, p.w0, __builtin_fmaf(x1, p.w1, p.bm1));
        float t2  = __builtin_fmaf(tau, tau, 1.0f);
        float rq  = __builtin_amdgcn_rsqf(t2);
        float gc  = tau * rq;
        float f0  = __builtin_fmaf(-gc, p.hw0, e0);    // no-kink branch const
        float f0k = __builtin_fmaf(-gc, p.hw0, e0k);   // kink branch const
        float f1  = __builtin_fmaf(-gc, p.hw1, e1);
        float f1k = __builtin_fmaf(-gc, p.hw1, e1k);
#pragma unroll
        for (int h = 0; h < 4; ++h) {
            float q  = __builtin_fmaf(x0, p.v0, __builtin_fmaf(x1, p.v1, p.mvr));
            float a0 = (q > 0.0f) ? f0k : f0;
            float a1 = (q > 0.0f) ? f1k : f1;
            x0 = clampx(__builtin_fmaf(0.95f, x0, a0));
            x1 = clampx(__builtin_fmaf(0.95f, x1, a1));
        }
    }
    ox0 = x0;
    ox1 = x1;
}

__global__ __launch_bounds__(256, 8)
void strategic_kernel(const float* __restrict__ X,
                      const float* __restrict__ wp,
                      const float* __restrict__ bp,
                      const float* __restrict__ vp,
                      float* __restrict__ out, int B) {
    int i = blockIdx.x * blockDim.x + threadIdx.x;
    if (i >= B) return;

    const float w0 = wp[0], w1 = wp[1], b = bp[0], v0 = vp[0], v1 = vp[1];

    P p;
    p.w0 = w0; p.w1 = w1; p.v0 = v0; p.v1 = v1;
    p.bm1 = b - 1.0f;
    p.hw0 = 0.5f * w0; p.hw1 = 0.5f * w1;
    const float bp1 = b + 1.0f;
    const float k0 = 0.475f * v0, k1 = 0.475f * v1;   // COST*(1-EPS)*v

    float2 r = reinterpret_cast<const float2*>(X)[i];
    const float r0 = r.x, r1 = r.y;

    const float sx0 = clampx(r0), sx1 = clampx(r1);   // inner-solve start
    p.mvr = -(__builtin_fmaf(r1, v1, r0 * v0));
    const float p5r0 = 0.05f * r0, p5r1 = 0.05f * r1;
    float xt0 = r0, xt1 = r1;                         // CCP state

    // fc history; NaN init => gates stay closed for first rounds
    float fc_p1 = __builtin_nanf(""), fc_p2 = __builtin_nanf("");
    float e0, e1, e0k, e1k;

    int c = 0;
    for (; c < 11; ++c) {
        // fder at xt (NR-refined rsq; 11 calls, cheap)
        float sp = __builtin_fmaf(xt0, p.w0, __builtin_fmaf(xt1, p.w1, bp1));
        float tt = __builtin_fmaf(sp, sp, 1.0f);
        float rs = rsq_nr(tt);
        float fc = (0.5f * sp) * rs;
        e0 = __builtin_fmaf(fc, p.w0, p5r0);
        e1 = __builtin_fmaf(fc, p.w1, p5r1);
        e0k = e0 - k0;
        e1k = e1 - k1;

        // Approximate convergence gates (wave-uniform). NaN-safe: compares
        // with NaN are false. Error vs reference trajectory bounded by
        // tau*(10-c)*20*|w|^2 <= 0.04.
        bool per1 = __builtin_fabsf(fc - fc_p1) <= TAU_CONV;
        bool per2 = __builtin_fabsf(fc - fc_p2) <= TAU_CONV;
        if (__all(per1) || (__all(per2) && ((10 - c) & 1))) break;
        fc_p2 = fc_p1;
        fc_p1 = fc;

        solve(25, sx0, sx1, e0, e1, e0k, e1k, p, xt0, xt1);  // 100 steps
    }

    if (c == 11) {   // natural exhaust: e-consts are fd(S_9); refresh at S_10
        float sp = __builtin_fmaf(xt0, p.w0, __builtin_fmaf(xt1, p.w1, bp1));
        float tt = __builtin_fmaf(sp, sp, 1.0f);
        float rs = rsq_nr(tt);
        float fc = (0.5f * sp) * rs;
        e0 = __builtin_fmaf(fc, p.w0, p5r0);
        e1 = __builtin_fmaf(fc, p.w1, p5r1);
        e0k = e0 - k0;
        e1k = e1 - k1;
    }

    // Final (differentiable) solve: 200 steps = 50 blocks
    float x0, x1;
    solve(50, sx0, sx1, e0, e1, e0k, e1k, p, x0, x1);

    out[i] = __builtin_fmaf(x0, p.w0, __builtin_fmaf(x1, p.w1, b));
}

extern "C" void kernel_launch(void* const* d_in, const int* in_sizes, int n_in,
                              void* d_out, int out_size, void* d_ws, size_t ws_size,
                              hipStream_t stream) {
    const float* X = (const float*)d_in[0];
    const float* w = (const float*)d_in[1];
    const float* b = (const float*)d_in[2];
    const float* v = (const float*)d_in[3];
    float* out = (float*)d_out;

    int B = in_sizes[0] / 2;   // X is [B, 2], 1 sample per thread
    int block = 256;
    int grid = (B + block - 1) / block;
    strategic_kernel<<<grid, block, 0, stream>>>(X, w, b, v, out, B);
}

// Round 5
// 139.125 us; speedup vs baseline: 4.4037x; 1.0673x over previous
//
#include <hip/hip_runtime.h>

// Problem: MyStrategicModel_35691178229867
// R13: R12 WIN (184->104us, absmax bit-identical 0.015625) -- approx
// convergence gate fires at avg ~5.3/11 rounds. This round, two
// independently-revertible cuts with separate error budgets:
//  (a) tau 2e-4 -> 4e-4. Contraction-free bound: reference runs only
//      (10-c) more rounds => remaining fc movement <= 10*tau, output
//      shift <= 20*|w|^2*10*tau <= 0.08 worst (|w|^2=1), ~0.026 typical.
//  (b) final solve 200 -> 140 steps (35 blocks). Rigorous: 0.95-contraction,
//      |x140-x200| <= 0.95^140 * 17 ~= 0.013 -> output <= 0.009.
//  Inner 100-step solves NOT touched: e-const error amplified 20x by final
//  solve (needs xt err < 1e-2 => k>=148). In-solve bitwise exit ruled out
//  (step movement ~1.5e-3 >> ulp at step 100).
// Error budget: 0.0156 + 0.08 + 0.009 ~= 0.105 worst, ~0.05 expected
// (threshold 0.13125). Predict dispatch 104 -> 80-93us.
// If absmax > 0.10: revert (a), keep (b).

#define XLO -10.0f
#define XHI 10.0f
#define TAU_CONV 4e-4f

__device__ __forceinline__ float clampx(float x) {
    return __builtin_amdgcn_fmed3f(x, XLO, XHI);   // v_med3_f32, x finite
}

__device__ __forceinline__ float rsq_nr(float t) {
    float y = __builtin_amdgcn_rsqf(t);
    float c = __builtin_fmaf(-0.5f * (t * y), y, 1.5f);
    return y * c;
}

struct P {
    float w0, w1, v0, v1, bm1, hw0, hw1, mvr;
};

// nblocks blocks of 4 PGA steps; gc refreshed per block, folded into the
// kink-branch constants f*/f*k. Kink test + clip exact per step.
// Byte-identical math to R12's solve().
__device__ __forceinline__ void solve(int nblocks, float sx0, float sx1,
                                      float e0, float e1, float e0k, float e1k,
                                      const P& p, float& ox0, float& ox1) {
    float x0 = sx0, x1 = sx1;
    for (int k = 0; k < nblocks; ++k) {
        float tau = __builtin_fmaf(x0, p.w0, __builtin_fmaf(x1, p.w1, p.bm1));
        float t2  = __builtin_fmaf(tau, tau, 1.0f);
        float rq  = __builtin_amdgcn_rsqf(t2);
        float gc  = tau * rq;
        float f0  = __builtin_fmaf(-gc, p.hw0, e0);    // no-kink branch const
        float f0k = __builtin_fmaf(-gc, p.hw0, e0k);   // kink branch const
        float f1  = __builtin_fmaf(-gc, p.hw1, e1);
        float f1k = __builtin_fmaf(-gc, p.hw1, e1k);
#pragma unroll
        for (int h = 0; h < 4; ++h) {
            float q  = __builtin_fmaf(x0, p.v0, __builtin_fmaf(x1, p.v1, p.mvr));
            float a0 = (q > 0.0f) ? f0k : f0;
            float a1 = (q > 0.0f) ? f1k : f1;
            x0 = clampx(__builtin_fmaf(0.95f, x0, a0));
            x1 = clampx(__builtin_fmaf(0.95f, x1, a1));
        }
    }
    ox0 = x0;
    ox1 = x1;
}

__global__ __launch_bounds__(256, 8)
void strategic_kernel(const float* __restrict__ X,
                      const float* __restrict__ wp,
                      const float* __restrict__ bp,
                      const float* __restrict__ vp,
                      float* __restrict__ out, int B) {
    int i = blockIdx.x * blockDim.x + threadIdx.x;
    if (i >= B) return;

    const float w0 = wp[0], w1 = wp[1], b = bp[0], v0 = vp[0], v1 = vp[1];

    P p;
    p.w0 = w0; p.w1 = w1; p.v0 = v0; p.v1 = v1;
    p.bm1 = b - 1.0f;
    p.hw0 = 0.5f * w0; p.hw1 = 0.5f * w1;
    const float bp1 = b + 1.0f;
    const float k0 = 0.475f * v0, k1 = 0.475f * v1;   // COST*(1-EPS)*v

    float2 r = reinterpret_cast<const float2*>(X)[i];
    const float r0 = r.x, r1 = r.y;

    const float sx0 = clampx(r0), sx1 = clampx(r1);   // inner-solve start
    p.mvr = -(__builtin_fmaf(r1, v1, r0 * v0));
    const float p5r0 = 0.05f * r0, p5r1 = 0.05f * r1;
    float xt0 = r0, xt1 = r1;                         // CCP state

    // fc history; NaN init => gates stay closed for first rounds
    float fc_p1 = __builtin_nanf(""), fc_p2 = __builtin_nanf("");
    float e0, e1, e0k, e1k;

    int c = 0;
    for (; c < 11; ++c) {
        // fder at xt (NR-refined rsq; 11 calls, cheap)
        float sp = __builtin_fmaf(xt0, p.w0, __builtin_fmaf(xt1, p.w1, bp1));
        float tt = __builtin_fmaf(sp, sp, 1.0f);
        float rs = rsq_nr(tt);
        float fc = (0.5f * sp) * rs;
        e0 = __builtin_fmaf(fc, p.w0, p5r0);
        e1 = __builtin_fmaf(fc, p.w1, p5r1);
        e0k = e0 - k0;
        e1k = e1 - k1;

        // Approximate convergence gates (wave-uniform). NaN-safe: compares
        // with NaN are false. Reference runs only (10-c) more rounds =>
        // remaining movement <= 10*tau -> output shift <= 200*tau*|w|^2.
        bool per1 = __builtin_fabsf(fc - fc_p1) <= TAU_CONV;
        bool per2 = __builtin_fabsf(fc - fc_p2) <= TAU_CONV;
        if (__all(per1) || (__all(per2) && ((10 - c) & 1))) break;
        fc_p2 = fc_p1;
        fc_p1 = fc;

        solve(25, sx0, sx1, e0, e1, e0k, e1k, p, xt0, xt1);  // 100 steps
    }

    if (c == 11) {   // natural exhaust: e-consts are fd(S_9); refresh at S_10
        float sp = __builtin_fmaf(xt0, p.w0, __builtin_fmaf(xt1, p.w1, bp1));
        float tt = __builtin_fmaf(sp, sp, 1.0f);
        float rs = rsq_nr(tt);
        float fc = (0.5f * sp) * rs;
        e0 = __builtin_fmaf(fc, p.w0, p5r0);
        e1 = __builtin_fmaf(fc, p.w1, p5r1);
        e0k = e0 - k0;
        e1k = e1 - k1;
    }

    // Final (differentiable) solve, truncated: 140 steps = 35 blocks.
    // |x140 - x200| <= 0.95^140 * 17 ~= 0.013 -> output shift <= 0.009.
    float x0, x1;
    solve(35, sx0, sx1, e0, e1, e0k, e1k, p, x0, x1);

    out[i] = __builtin_fmaf(x0, p.w0, __builtin_fmaf(x1, p.w1, b));
}

extern "C" void kernel_launch(void* const* d_in, const int* in_sizes, int n_in,
                              void* d_out, int out_size, void* d_ws, size_t ws_size,
                              hipStream_t stream) {
    const float* X = (const float*)d_in[0];
    const float* w = (const float*)d_in[1];
    const float* b = (const float*)d_in[2];
    const float* v = (const float*)d_in[3];
    float* out = (float*)d_out;

    int B = in_sizes[0] / 2;   // X is [B, 2], 1 sample per thread
    int block = 256;
    int grid = (B + block - 1) / block;
    strategic_kernel<<<grid, block, 0, stream>>>(X, w, b, v, out, B);
}

// Round 7
// 127.779 us; speedup vs baseline: 4.7947x; 1.0888x over previous
//
#include <hip/hip_runtime.h>

// Problem: MyStrategicModel_35691178229867
// R15 == R14 resubmitted verbatim (R14 bench was an infra failure:
// "MI355X container failed twice" -- no kernel signal; do not mutate
// on zero evidence).
// R14: R13 WIN (104->92us, absmax still bf16-floor 0.015625 => bounds loose).
// Work left: ~510 inner + 140 final steps/wave. This round: warm-start the
// final solve for per1-fired waves. Rationale: per1 (__all |dfc|<=tau) =>
// final-map FP within 20*|w|*tau ~= 6e-3 of xt's own map FP, and xt is
// 100-step-converged (residual <= 0.95^100*D ~= 0.02). Start distance
// ~0.025 -> 40 steps: 0.95^40*0.025 ~= 3e-3 -> output shift ~2e-3.
// per2-fired waves: xt is WRONG-PHASE (fc 2-cycle) -> keep sx+140 exactly.
// Exhaust (c==11): keep sx+140. Branch is wave-uniform (gates are __all).
// Inner solves untouched (truncation there amplifies 20x via e-consts;
// worst-case rho=0.95 samples make it unsafe -- ruled out by arithmetic).
// Predict: dispatch 92 -> 76-82us if per1 dominates (R12/13 say it does);
// absmax 0.015625 -> <=0.02. If dur flat: waves exit via per2/exhaust.

#define XLO -10.0f
#define XHI 10.0f
#define TAU_CONV 4e-4f

__device__ __forceinline__ float clampx(float x) {
    return __builtin_amdgcn_fmed3f(x, XLO, XHI);   // v_med3_f32, x finite
}

__device__ __forceinline__ float rsq_nr(float t) {
    float y = __builtin_amdgcn_rsqf(t);
    float c = __builtin_fmaf(-0.5f * (t * y), y, 1.5f);
    return y * c;
}

struct P {
    float w0, w1, v0, v1, bm1, hw0, hw1, mvr;
};

// nblocks blocks of 4 PGA steps; gc refreshed per block, folded into the
// kink-branch constants f*/f*k. Kink test + clip exact per step.
// Byte-identical math to R13's solve().
__device__ __forceinline__ void solve(int nblocks, float sx0, float sx1,
                                      float e0, float e1, float e0k, float e1k,
                                      const P& p, float& ox0, float& ox1) {
    float x0 = sx0, x1 = sx1;
    for (int k = 0; k < nblocks; ++k) {
        float tau = __builtin_fmaf(x0, p.w0, __builtin_fmaf(x1, p.w1, p.bm1));
        float t2  = __builtin_fmaf(tau, tau, 1.0f);
        float rq  = __builtin_amdgcn_rsqf(t2);
        float gc  = tau * rq;
        float f0  = __builtin_fmaf(-gc, p.hw0, e0);    // no-kink branch const
        float f0k = __builtin_fmaf(-gc, p.hw0, e0k);   // kink branch const
        float f1  = __builtin_fmaf(-gc, p.hw1, e1);
        float f1k = __builtin_fmaf(-gc, p.hw1, e1k);
#pragma unroll
        for (int h = 0; h < 4; ++h) {
            float q  = __builtin_fmaf(x0, p.v0, __builtin_fmaf(x1, p.v1, p.mvr));
            float a0 = (q > 0.0f) ? f0k : f0;
            float a1 = (q > 0.0f) ? f1k : f1;
            x0 = clampx(__builtin_fmaf(0.95f, x0, a0));
            x1 = clampx(__builtin_fmaf(0.95f, x1, a1));
        }
    }
    ox0 = x0;
    ox1 = x1;
}

__global__ __launch_bounds__(256, 8)
void strategic_kernel(const float* __restrict__ X,
                      const float* __restrict__ wp,
                      const float* __restrict__ bp,
                      const float* __restrict__ vp,
                      float* __restrict__ out, int B) {
    int i = blockIdx.x * blockDim.x + threadIdx.x;
    if (i >= B) return;

    const float w0 = wp[0], w1 = wp[1], b = bp[0], v0 = vp[0], v1 = vp[1];

    P p;
    p.w0 = w0; p.w1 = w1; p.v0 = v0; p.v1 = v1;
    p.bm1 = b - 1.0f;
    p.hw0 = 0.5f * w0; p.hw1 = 0.5f * w1;
    const float bp1 = b + 1.0f;
    const float k0 = 0.475f * v0, k1 = 0.475f * v1;   // COST*(1-EPS)*v

    float2 r = reinterpret_cast<const float2*>(X)[i];
    const float r0 = r.x, r1 = r.y;

    const float sx0 = clampx(r0), sx1 = clampx(r1);   // inner-solve start
    p.mvr = -(__builtin_fmaf(r1, v1, r0 * v0));
    const float p5r0 = 0.05f * r0, p5r1 = 0.05f * r1;
    float xt0 = r0, xt1 = r1;                         // CCP state

    // fc history; NaN init => gates stay closed for first rounds
    float fc_p1 = __builtin_nanf(""), fc_p2 = __builtin_nanf("");
    float e0, e1, e0k, e1k;

    int mode = 0;   // 0 = exhaust/none, 1 = per1 break, 2 = per2 break
    int c = 0;
    for (; c < 11; ++c) {
        // fder at xt (NR-refined rsq; 11 calls, cheap)
        float sp = __builtin_fmaf(xt0, p.w0, __builtin_fmaf(xt1, p.w1, bp1));
        float tt = __builtin_fmaf(sp, sp, 1.0f);
        float rs = rsq_nr(tt);
        float fc = (0.5f * sp) * rs;
        e0 = __builtin_fmaf(fc, p.w0, p5r0);
        e1 = __builtin_fmaf(fc, p.w1, p5r1);
        e0k = e0 - k0;
        e1k = e1 - k1;

        // Approximate convergence gates (wave-uniform, NaN-safe).
        bool per1 = __builtin_fabsf(fc - fc_p1) <= TAU_CONV;
        bool per2 = __builtin_fabsf(fc - fc_p2) <= TAU_CONV;
        if (__all(per1)) { mode = 1; break; }
        if (__all(per2) && ((10 - c) & 1)) { mode = 2; break; }
        fc_p2 = fc_p1;
        fc_p1 = fc;

        solve(25, sx0, sx1, e0, e1, e0k, e1k, p, xt0, xt1);  // 100 steps
    }

    if (c == 11) {   // natural exhaust: e-consts are fd(S_9); refresh at S_10
        float sp = __builtin_fmaf(xt0, p.w0, __builtin_fmaf(xt1, p.w1, bp1));
        float tt = __builtin_fmaf(sp, sp, 1.0f);
        float rs = rsq_nr(tt);
        float fc = (0.5f * sp) * rs;
        e0 = __builtin_fmaf(fc, p.w0, p5r0);
        e1 = __builtin_fmaf(fc, p.w1, p5r1);
        e0k = e0 - k0;
        e1k = e1 - k1;
    }

    // Final (differentiable) solve.
    // per1 waves: warm-start from xt (already ~0.025 from the final FP),
    //   40 steps -> residual ~3e-3. per2/exhaust: exact R13 path (sx, 140).
    float x0, x1;
    if (mode == 1) {
        solve(10, xt0, xt1, e0, e1, e0k, e1k, p, x0, x1);   // 40 steps
    } else {
        solve(35, sx0, sx1, e0, e1, e0k, e1k, p, x0, x1);   // 140 steps
    }

    out[i] = __builtin_fmaf(x0, p.w0, __builtin_fmaf(x1, p.w1, b));
}

extern "C" void kernel_launch(void* const* d_in, const int* in_sizes, int n_in,
                              void* d_out, int out_size, void* d_ws, size_t ws_size,
                              hipStream_t stream) {
    const float* X = (const float*)d_in[0];
    const float* w = (const float*)d_in[1];
    const float* b = (const float*)d_in[2];
    const float* v = (const float*)d_in[3];
    float* out = (float*)d_out;

    int B = in_sizes[0] / 2;   // X is [B, 2], 1 sample per thread
    int block = 256;
    int grid = (B + block - 1) / block;
    strategic_kernel<<<grid, block, 0, stream>>>(X, w, b, v, out, B);
}

// Round 8
// 101.756 us; speedup vs baseline: 6.0209x; 1.2557x over previous
//
#include <hip/hip_runtime.h>

// Problem: MyStrategicModel_35691178229867
// R16: R15 WIN (92->79.5us, absmax bit-floor). Single change this round:
// WARM-START CHAINING of inner CCP solves. Round 0: cold 100 steps from sx
// (reference-faithful). Rounds >=1: warm-start from previous xt, 48 steps.
// Why safe where R11 failed: R11 biased the MAP (stale gc => shifted FP,
// 3.71 blowup). Warm-start keeps the map exact -- same FP, and contraction
// erases start-point differences. At gate-fire the warm chain's residual
// (~0.01) is SMALLER than the reference's cold-100 residual (~0.02-0.06,
// calibrated by R15: 40-step warm final was bit-neutral => |xt-FP| <= 0.1).
// Only deviation = reference's own truncation bias, <= ~0.06 output worst,
// realized ~10x looser in all prior rounds.
// Gate/break/final logic identical to R15 (per1 -> 40-step warm final;
// per2/exhaust -> cold 140 from sx).
// Predict: steps 550 -> ~346, dispatch 79.5 -> 52-62us, absmax 0.015625
// (accept <=0.05; on fail revert to 72-step warm rounds).

#define XLO -10.0f
#define XHI 10.0f
#define TAU_CONV 4e-4f

__device__ __forceinline__ float clampx(float x) {
    return __builtin_amdgcn_fmed3f(x, XLO, XHI);   // v_med3_f32, x finite
}

__device__ __forceinline__ float rsq_nr(float t) {
    float y = __builtin_amdgcn_rsqf(t);
    float c = __builtin_fmaf(-0.5f * (t * y), y, 1.5f);
    return y * c;
}

struct P {
    float w0, w1, v0, v1, bm1, hw0, hw1, mvr;
};

// nblocks blocks of 4 PGA steps; gc refreshed per block, folded into the
// kink-branch constants f*/f*k. Kink test + clip exact per step.
// Byte-identical math to R15's solve().
__device__ __forceinline__ void solve(int nblocks, float sx0, float sx1,
                                      float e0, float e1, float e0k, float e1k,
                                      const P& p, float& ox0, float& ox1) {
    float x0 = sx0, x1 = sx1;
    for (int k = 0; k < nblocks; ++k) {
        float tau = __builtin_fmaf(x0, p.w0, __builtin_fmaf(x1, p.w1, p.bm1));
        float t2  = __builtin_fmaf(tau, tau, 1.0f);
        float rq  = __builtin_amdgcn_rsqf(t2);
        float gc  = tau * rq;
        float f0  = __builtin_fmaf(-gc, p.hw0, e0);    // no-kink branch const
        float f0k = __builtin_fmaf(-gc, p.hw0, e0k);   // kink branch const
        float f1  = __builtin_fmaf(-gc, p.hw1, e1);
        float f1k = __builtin_fmaf(-gc, p.hw1, e1k);
#pragma unroll
        for (int h = 0; h < 4; ++h) {
            float q  = __builtin_fmaf(x0, p.v0, __builtin_fmaf(x1, p.v1, p.mvr));
            float a0 = (q > 0.0f) ? f0k : f0;
            float a1 = (q > 0.0f) ? f1k : f1;
            x0 = clampx(__builtin_fmaf(0.95f, x0, a0));
            x1 = clampx(__builtin_fmaf(0.95f, x1, a1));
        }
    }
    ox0 = x0;
    ox1 = x1;
}

__global__ __launch_bounds__(256, 8)
void strategic_kernel(const float* __restrict__ X,
                      const float* __restrict__ wp,
                      const float* __restrict__ bp,
                      const float* __restrict__ vp,
                      float* __restrict__ out, int B) {
    int i = blockIdx.x * blockDim.x + threadIdx.x;
    if (i >= B) return;

    const float w0 = wp[0], w1 = wp[1], b = bp[0], v0 = vp[0], v1 = vp[1];

    P p;
    p.w0 = w0; p.w1 = w1; p.v0 = v0; p.v1 = v1;
    p.bm1 = b - 1.0f;
    p.hw0 = 0.5f * w0; p.hw1 = 0.5f * w1;
    const float bp1 = b + 1.0f;
    const float k0 = 0.475f * v0, k1 = 0.475f * v1;   // COST*(1-EPS)*v

    float2 r = reinterpret_cast<const float2*>(X)[i];
    const float r0 = r.x, r1 = r.y;

    const float sx0 = clampx(r0), sx1 = clampx(r1);   // inner-solve start
    p.mvr = -(__builtin_fmaf(r1, v1, r0 * v0));
    const float p5r0 = 0.05f * r0, p5r1 = 0.05f * r1;
    float xt0 = r0, xt1 = r1;                         // CCP state

    // fc history; NaN init => gates stay closed for first rounds
    float fc_p1 = __builtin_nanf(""), fc_p2 = __builtin_nanf("");
    float e0, e1, e0k, e1k;

    int mode = 0;   // 0 = exhaust/none, 1 = per1 break, 2 = per2 break
    int c = 0;
    for (; c < 11; ++c) {
        // fder at xt (NR-refined rsq; 11 calls, cheap)
        float sp = __builtin_fmaf(xt0, p.w0, __builtin_fmaf(xt1, p.w1, bp1));
        float tt = __builtin_fmaf(sp, sp, 1.0f);
        float rs = rsq_nr(tt);
        float fc = (0.5f * sp) * rs;
        e0 = __builtin_fmaf(fc, p.w0, p5r0);
        e1 = __builtin_fmaf(fc, p.w1, p5r1);
        e0k = e0 - k0;
        e1k = e1 - k1;

        // Approximate convergence gates (wave-uniform, NaN-safe).
        bool per1 = __builtin_fabsf(fc - fc_p1) <= TAU_CONV;
        bool per2 = __builtin_fabsf(fc - fc_p2) <= TAU_CONV;
        if (__all(per1)) { mode = 1; break; }
        if (__all(per2) && ((10 - c) & 1)) { mode = 2; break; }
        fc_p2 = fc_p1;
        fc_p1 = fc;

        if (c == 0) {
            solve(25, sx0, sx1, e0, e1, e0k, e1k, p, xt0, xt1);  // cold 100
        } else {
            solve(12, xt0, xt1, e0, e1, e0k, e1k, p, xt0, xt1);  // warm 48
        }
    }

    if (c == 11) {   // natural exhaust: e-consts refreshed at the last state
        float sp = __builtin_fmaf(xt0, p.w0, __builtin_fmaf(xt1, p.w1, bp1));
        float tt = __builtin_fmaf(sp, sp, 1.0f);
        float rs = rsq_nr(tt);
        float fc = (0.5f * sp) * rs;
        e0 = __builtin_fmaf(fc, p.w0, p5r0);
        e1 = __builtin_fmaf(fc, p.w1, p5r1);
        e0k = e0 - k0;
        e1k = e1 - k1;
    }

    // Final (differentiable) solve.
    // per1 waves: warm-start from xt, 40 steps (R15-proven bit-neutral).
    // per2/exhaust: cold from sx, 140 steps (R13-proven).
    float x0, x1;
    if (mode == 1) {
        solve(10, xt0, xt1, e0, e1, e0k, e1k, p, x0, x1);   // 40 steps
    } else {
        solve(35, sx0, sx1, e0, e1, e0k, e1k, p, x0, x1);   // 140 steps
    }

    out[i] = __builtin_fmaf(x0, p.w0, __builtin_fmaf(x1, p.w1, b));
}

extern "C" void kernel_launch(void* const* d_in, const int* in_sizes, int n_in,
                              void* d_out, int out_size, void* d_ws, size_t ws_size,
                              hipStream_t stream) {
    const float* X = (const float*)d_in[0];
    const float* w = (const float*)d_in[1];
    const float* b = (const float*)d_in[2];
    const float* v = (const float*)d_in[3];
    float* out = (float*)d_out;

    int B = in_sizes[0] / 2;   // X is [B, 2], 1 sample per thread
    int block = 256;
    int grid = (B + block - 1) / block;
    strategic_kernel<<<grid, block, 0, stream>>>(X, w, b, v, out, B);
}

// Round 9
// 88.055 us; speedup vs baseline: 6.9578x; 1.1556x over previous
//
#include <hip/hip_runtime.h>

// Problem: MyStrategicModel_35691178229867
// R17: R16 WIN (79.5->51us, absmax 0.03125 = +1 bf16 ulp). New lever:
// TWO-SPEED SOLVES. Projected-gradient FPs are step-size-independent
// (KKT has no lambda); L <= 0.1+0.25|w|^2 <= 0.35 so lambda=2 contracts
// at 0.90/step (vs 0.95) and converges to the SAME FP. Each solve =
// lambda=2 main phase + even lambda=1 tail (8 steps) to restore
// reference kink-oscillation amplitude/parity. gc staleness in lambda=2
// phase: refreshed every 2 steps = movement of 4 lambda=1 steps = R8's
// proven-bit-neutral scale (NOT R11's failed 10-step scale).
// Cadences (residual-matched): cold 100 -> 44@l2+8@l1; warm 48 -> 16+8;
// final-warm 40 -> 16+8; final-cold 140 -> 60+8. Net work ~0.59x.
// Predict: dispatch 51 -> 27-35us; absmax <= 0.0625 (revert if > 0.1).

#define XLO -10.0f
#define XHI 10.0f
#define TAU_CONV 4e-4f

__device__ __forceinline__ float clampx(float x) {
    return __builtin_amdgcn_fmed3f(x, XLO, XHI);   // v_med3_f32, x finite
}

__device__ __forceinline__ float rsq_nr(float t) {
    float y = __builtin_amdgcn_rsqf(t);
    float c = __builtin_fmaf(-0.5f * (t * y), y, 1.5f);
    return y * c;
}

struct P {
    float w0, w1, v0, v1, bm1, hw0, hw1, mvr;
};

// lambda=1 solve: blocks of 4 steps, gc refreshed per block (R8-proven).
// Byte-identical math to R16's solve().
__device__ __forceinline__ void solve(int nblocks, float sx0, float sx1,
                                      float e0, float e1, float e0k, float e1k,
                                      const P& p, float& ox0, float& ox1) {
    float x0 = sx0, x1 = sx1;
    for (int k = 0; k < nblocks; ++k) {
        float tau = __builtin_fmaf(x0, p.w0, __builtin_fmaf(x1, p.w1, p.bm1));
        float t2  = __builtin_fmaf(tau, tau, 1.0f);
        float rq  = __builtin_amdgcn_rsqf(t2);
        float gc  = tau * rq;
        float f0  = __builtin_fmaf(-gc, p.hw0, e0);    // no-kink branch const
        float f0k = __builtin_fmaf(-gc, p.hw0, e0k);   // kink branch const
        float f1  = __builtin_fmaf(-gc, p.hw1, e1);
        float f1k = __builtin_fmaf(-gc, p.hw1, e1k);
#pragma unroll
        for (int h = 0; h < 4; ++h) {
            float q  = __builtin_fmaf(x0, p.v0, __builtin_fmaf(x1, p.v1, p.mvr));
            float a0 = (q > 0.0f) ? f0k : f0;
            float a1 = (q > 0.0f) ? f1k : f1;
            x0 = clampx(__builtin_fmaf(0.95f, x0, a0));
            x1 = clampx(__builtin_fmaf(0.95f, x1, a1));
        }
    }
    ox0 = x0;
    ox1 = x1;
}

// lambda=2 solve: blocks of 2 steps, gc refreshed per block. Update:
// x <- clip(0.90*x + 2*(e - gc*hw - kink)). Doubled additive consts are
// passed in (e*d); 2*hw == w, so the gc fold uses p.w directly.
// gc-staleness per refresh window == R8's proven 4-step lambda=1 scale.
__device__ __forceinline__ void solve2(int nblocks, float sx0, float sx1,
                                       float e0d, float e1d, float e0kd, float e1kd,
                                       const P& p, float& ox0, float& ox1) {
    float x0 = sx0, x1 = sx1;
    for (int k = 0; k < nblocks; ++k) {
        float tau = __builtin_fmaf(x0, p.w0, __builtin_fmaf(x1, p.w1, p.bm1));
        float t2  = __builtin_fmaf(tau, tau, 1.0f);
        float rq  = __builtin_amdgcn_rsqf(t2);
        float gc  = tau * rq;
        float f0  = __builtin_fmaf(-gc, p.w0, e0d);    // 2*hw0 = w0
        float f0k = __builtin_fmaf(-gc, p.w0, e0kd);
        float f1  = __builtin_fmaf(-gc, p.w1, e1d);
        float f1k = __builtin_fmaf(-gc, p.w1, e1kd);
#pragma unroll
        for (int h = 0; h < 2; ++h) {
            float q  = __builtin_fmaf(x0, p.v0, __builtin_fmaf(x1, p.v1, p.mvr));
            float a0 = (q > 0.0f) ? f0k : f0;
            float a1 = (q > 0.0f) ? f1k : f1;
            x0 = clampx(__builtin_fmaf(0.90f, x0, a0));
            x1 = clampx(__builtin_fmaf(0.90f, x1, a1));
        }
    }
    ox0 = x0;
    ox1 = x1;
}

__global__ __launch_bounds__(256, 8)
void strategic_kernel(const float* __restrict__ X,
                      const float* __restrict__ wp,
                      const float* __restrict__ bp,
                      const float* __restrict__ vp,
                      float* __restrict__ out, int B) {
    int i = blockIdx.x * blockDim.x + threadIdx.x;
    if (i >= B) return;

    const float w0 = wp[0], w1 = wp[1], b = bp[0], v0 = vp[0], v1 = vp[1];

    P p;
    p.w0 = w0; p.w1 = w1; p.v0 = v0; p.v1 = v1;
    p.bm1 = b - 1.0f;
    p.hw0 = 0.5f * w0; p.hw1 = 0.5f * w1;
    const float bp1 = b + 1.0f;
    const float k0 = 0.475f * v0, k1 = 0.475f * v1;   // COST*(1-EPS)*v

    float2 r = reinterpret_cast<const float2*>(X)[i];
    const float r0 = r.x, r1 = r.y;

    const float sx0 = clampx(r0), sx1 = clampx(r1);   // inner-solve start
    p.mvr = -(__builtin_fmaf(r1, v1, r0 * v0));
    const float p5r0 = 0.05f * r0, p5r1 = 0.05f * r1;
    float xt0 = r0, xt1 = r1;                         // CCP state

    // fc history; NaN init => gates stay closed for first rounds
    float fc_p1 = __builtin_nanf(""), fc_p2 = __builtin_nanf("");
    float e0, e1, e0k, e1k, e0d, e1d, e0kd, e1kd;

    int mode = 0;   // 0 = exhaust/none, 1 = per1 break, 2 = per2 break
    int c = 0;
    for (; c < 11; ++c) {
        // fder at xt (NR-refined rsq; 11 calls, cheap)
        float sp = __builtin_fmaf(xt0, p.w0, __builtin_fmaf(xt1, p.w1, bp1));
        float tt = __builtin_fmaf(sp, sp, 1.0f);
        float rs = rsq_nr(tt);
        float fc = (0.5f * sp) * rs;
        e0 = __builtin_fmaf(fc, p.w0, p5r0);
        e1 = __builtin_fmaf(fc, p.w1, p5r1);
        e0k = e0 - k0;
        e1k = e1 - k1;
        e0d = e0 + e0; e1d = e1 + e1; e0kd = e0k + e0k; e1kd = e1k + e1k;

        // Approximate convergence gates (wave-uniform, NaN-safe).
        bool per1 = __builtin_fabsf(fc - fc_p1) <= TAU_CONV;
        bool per2 = __builtin_fabsf(fc - fc_p2) <= TAU_CONV;
        if (__all(per1)) { mode = 1; break; }
        if (__all(per2) && ((10 - c) & 1)) { mode = 2; break; }
        fc_p2 = fc_p1;
        fc_p1 = fc;

        if (c == 0) {
            // cold: 44 steps @ lambda=2 + 8 steps @ lambda=1
            solve2(22, sx0, sx1, e0d, e1d, e0kd, e1kd, p, xt0, xt1);
            solve(2, xt0, xt1, e0, e1, e0k, e1k, p, xt0, xt1);
        } else {
            // warm: 16 steps @ lambda=2 + 8 steps @ lambda=1
            solve2(8, xt0, xt1, e0d, e1d, e0kd, e1kd, p, xt0, xt1);
            solve(2, xt0, xt1, e0, e1, e0k, e1k, p, xt0, xt1);
        }
    }

    if (c == 11) {   // natural exhaust: e-consts refreshed at the last state
        float sp = __builtin_fmaf(xt0, p.w0, __builtin_fmaf(xt1, p.w1, bp1));
        float tt = __builtin_fmaf(sp, sp, 1.0f);
        float rs = rsq_nr(tt);
        float fc = (0.5f * sp) * rs;
        e0 = __builtin_fmaf(fc, p.w0, p5r0);
        e1 = __builtin_fmaf(fc, p.w1, p5r1);
        e0k = e0 - k0;
        e1k = e1 - k1;
        e0d = e0 + e0; e1d = e1 + e1; e0kd = e0k + e0k; e1kd = e1k + e1k;
    }

    // Final (differentiable) solve, two-speed.
    float x0, x1;
    if (mode == 1) {
        // warm: 16 @ l2 + 8 @ l1 (residual ~= R15's proven 40 @ l1)
        solve2(8, xt0, xt1, e0d, e1d, e0kd, e1kd, p, x0, x1);
        solve(2, x0, x1, e0, e1, e0k, e1k, p, x0, x1);
    } else {
        // cold: 60 @ l2 + 8 @ l1 (residual ~= R13's proven 140 @ l1)
        solve2(30, sx0, sx1, e0d, e1d, e0kd, e1kd, p, x0, x1);
        solve(2, x0, x1, e0, e1, e0k, e1k, p, x0, x1);
    }

    out[i] = __builtin_fmaf(x0, p.w0, __builtin_fmaf(x1, p.w1, b));
}

extern "C" void kernel_launch(void* const* d_in, const int* in_sizes, int n_in,
                              void* d_out, int out_size, void* d_ws, size_t ws_size,
                              hipStream_t stream) {
    const float* X = (const float*)d_in[0];
    const float* w = (const float*)d_in[1];
    const float* b = (const float*)d_in[2];
    const float* v = (const float*)d_in[3];
    float* out = (float*)d_out;

    int B = in_sizes[0] / 2;   // X is [B, 2], 1 sample per thread
    int block = 256;
    int grid = (B + block - 1) / block;
    strategic_kernel<<<grid, block, 0, stream>>>(X, w, b, v, out, B);
}

// Round 10
// 79.557 us; speedup vs baseline: 7.7010x; 1.1068x over previous
//
#include <hip/hip_runtime.h>

// Problem: MyStrategicModel_35691178229867
// R18: R17 WIN (bench 101.8->88.1, absmax held 0.03125; kernel now below
// the harness's 40us fillBuffer memsets in top-5 -- ignore those rows).
// Single lever this round: lambda=4 with PER-STEP gc refresh.
//  - Staleness criterion is movement-per-refresh-window: 1 step @ l4 =
//    4 l1-units = R8's proven scale (R11 failed at 10 units).
//  - Stability: smooth Jacobian eigenvalues at l4 in [0.3,0.8], contraction
//    0.80/step vs 0.90 (l2). lambda < 2/L ~= 5.7 with margin.
//  - Per-step refresh enables select-then-fold (select e-const by kink,
//    then one fma folds gc) -- bitwise-identical per step, 16 ops/step.
//  - Kink 2-cycle amplitude is 4x during l4 phase: FINAL solves step down
//    l4 -> 4@l2 -> 8@l1 (double damping); inner solves keep 4@l1 tail
//    (kink noise enters only via smooth fc).
// Residual-matched cadences (vs R17): cold 22@l4+4@l1; warm 10@l4+4@l1;
// final-warm 6@l4+4@l2+8@l1; final-cold 28@l4+4@l2+8@l1. All even.
// Gate/tau untouched. Op model 2306 -> ~1520 (0.66x).
// Predict: bench 88 -> 74-78us; absmax <= 0.0625 (revert to R17 if fail).

#define XLO -10.0f
#define XHI 10.0f
#define TAU_CONV 4e-4f

__device__ __forceinline__ float clampx(float x) {
    return __builtin_amdgcn_fmed3f(x, XLO, XHI);   // v_med3_f32, x finite
}

__device__ __forceinline__ float rsq_nr(float t) {
    float y = __builtin_amdgcn_rsqf(t);
    float c = __builtin_fmaf(-0.5f * (t * y), y, 1.5f);
    return y * c;
}

struct P {
    float w0, w1, v0, v1, bm1, hw0, hw1, mvr;
};

// lambda=1 solve: blocks of 4 steps, gc refreshed per block (R8-proven).
// Byte-identical math to R17's solve().
__device__ __forceinline__ void solve(int nblocks, float sx0, float sx1,
                                      float e0, float e1, float e0k, float e1k,
                                      const P& p, float& ox0, float& ox1) {
    float x0 = sx0, x1 = sx1;
    for (int k = 0; k < nblocks; ++k) {
        float tau = __builtin_fmaf(x0, p.w0, __builtin_fmaf(x1, p.w1, p.bm1));
        float t2  = __builtin_fmaf(tau, tau, 1.0f);
        float rq  = __builtin_amdgcn_rsqf(t2);
        float gc  = tau * rq;
        float f0  = __builtin_fmaf(-gc, p.hw0, e0);    // no-kink branch const
        float f0k = __builtin_fmaf(-gc, p.hw0, e0k);   // kink branch const
        float f1  = __builtin_fmaf(-gc, p.hw1, e1);
        float f1k = __builtin_fmaf(-gc, p.hw1, e1k);
#pragma unroll
        for (int h = 0; h < 4; ++h) {
            float q  = __builtin_fmaf(x0, p.v0, __builtin_fmaf(x1, p.v1, p.mvr));
            float a0 = (q > 0.0f) ? f0k : f0;
            float a1 = (q > 0.0f) ? f1k : f1;
            x0 = clampx(__builtin_fmaf(0.95f, x0, a0));
            x1 = clampx(__builtin_fmaf(0.95f, x1, a1));
        }
    }
    ox0 = x0;
    ox1 = x1;
}

// lambda=2 solve: blocks of 2 steps, gc refreshed per block (R17-proven).
// Doubled additive consts passed in; 2*hw == w so the fold uses p.w.
__device__ __forceinline__ void solve2(int nblocks, float sx0, float sx1,
                                       float e0d, float e1d, float e0kd, float e1kd,
                                       const P& p, float& ox0, float& ox1) {
    float x0 = sx0, x1 = sx1;
    for (int k = 0; k < nblocks; ++k) {
        float tau = __builtin_fmaf(x0, p.w0, __builtin_fmaf(x1, p.w1, p.bm1));
        float t2  = __builtin_fmaf(tau, tau, 1.0f);
        float rq  = __builtin_amdgcn_rsqf(t2);
        float gc  = tau * rq;
        float f0  = __builtin_fmaf(-gc, p.w0, e0d);    // 2*hw0 = w0
        float f0k = __builtin_fmaf(-gc, p.w0, e0kd);
        float f1  = __builtin_fmaf(-gc, p.w1, e1d);
        float f1k = __builtin_fmaf(-gc, p.w1, e1kd);
#pragma unroll
        for (int h = 0; h < 2; ++h) {
            float q  = __builtin_fmaf(x0, p.v0, __builtin_fmaf(x1, p.v1, p.mvr));
            float a0 = (q > 0.0f) ? f0k : f0;
            float a1 = (q > 0.0f) ? f1k : f1;
            x0 = clampx(__builtin_fmaf(0.90f, x0, a0));
            x1 = clampx(__builtin_fmaf(0.90f, x1, a1));
        }
    }
    ox0 = x0;
    ox1 = x1;
}

// lambda=4 solve: gc refreshed EVERY step (staleness window = 4 l1-units =
// R8 scale). Quadrupled additive consts passed in; lambda*hw = 2*w (tw).
// Select-then-fold: a = fma(-gc, tw, sel(q, ekq, eq)) -- bitwise equal to
// fold-then-select, 2 fma cheaper per step (16 ops/step).
__device__ __forceinline__ void solve4(int nsteps, float sx0, float sx1,
                                       float e0q, float e1q, float e0kq, float e1kq,
                                       float tw0, float tw1,
                                       const P& p, float& ox0, float& ox1) {
    float x0 = sx0, x1 = sx1;
#pragma unroll 2
    for (int k = 0; k < nsteps; ++k) {
        float q    = __builtin_fmaf(x0, p.v0, __builtin_fmaf(x1, p.v1, p.mvr));
        float sel0 = (q > 0.0f) ? e0kq : e0q;
        float sel1 = (q > 0.0f) ? e1kq : e1q;
        float tau = __builtin_fmaf(x0, p.w0, __builtin_fmaf(x1, p.w1, p.bm1));
        float t2  = __builtin_fmaf(tau, tau, 1.0f);
        float rq  = __builtin_amdgcn_rsqf(t2);
        float gc  = tau * rq;
        float a0  = __builtin_fmaf(-gc, tw0, sel0);
        float a1  = __builtin_fmaf(-gc, tw1, sel1);
        x0 = clampx(__builtin_fmaf(0.80f, x0, a0));
        x1 = clampx(__builtin_fmaf(0.80f, x1, a1));
    }
    ox0 = x0;
    ox1 = x1;
}

__global__ __launch_bounds__(256, 8)
void strategic_kernel(const float* __restrict__ X,
                      const float* __restrict__ wp,
                      const float* __restrict__ bp,
                      const float* __restrict__ vp,
                      float* __restrict__ out, int B) {
    int i = blockIdx.x * blockDim.x + threadIdx.x;
    if (i >= B) return;

    const float w0 = wp[0], w1 = wp[1], b = bp[0], v0 = vp[0], v1 = vp[1];

    P p;
    p.w0 = w0; p.w1 = w1; p.v0 = v0; p.v1 = v1;
    p.bm1 = b - 1.0f;
    p.hw0 = 0.5f * w0; p.hw1 = 0.5f * w1;
    const float tw0 = w0 + w0, tw1 = w1 + w1;        // lambda4 * hw = 2w
    const float bp1 = b + 1.0f;
    const float k0 = 0.475f * v0, k1 = 0.475f * v1;  // COST*(1-EPS)*v

    float2 r = reinterpret_cast<const float2*>(X)[i];
    const float r0 = r.x, r1 = r.y;

    const float sx0 = clampx(r0), sx1 = clampx(r1);  // inner-solve start
    p.mvr = -(__builtin_fmaf(r1, v1, r0 * v0));
    const float p5r0 = 0.05f * r0, p5r1 = 0.05f * r1;
    float xt0 = r0, xt1 = r1;                        // CCP state

    // fc history; NaN init => gates stay closed for first rounds
    float fc_p1 = __builtin_nanf(""), fc_p2 = __builtin_nanf("");
    float e0, e1, e0k, e1k;
    float e0d, e1d, e0kd, e1kd;      // x2 (lambda2)
    float e0q, e1q, e0kq, e1kq;      // x4 (lambda4)

    int mode = 0;   // 0 = exhaust/none, 1 = per1 break, 2 = per2 break
    int c = 0;
    for (; c < 11; ++c) {
        // fder at xt (NR-refined rsq; 11 calls, cheap)
        float sp = __builtin_fmaf(xt0, p.w0, __builtin_fmaf(xt1, p.w1, bp1));
        float tt = __builtin_fmaf(sp, sp, 1.0f);
        float rs = rsq_nr(tt);
        float fc = (0.5f * sp) * rs;
        e0 = __builtin_fmaf(fc, p.w0, p5r0);
        e1 = __builtin_fmaf(fc, p.w1, p5r1);
        e0k = e0 - k0;
        e1k = e1 - k1;
        e0d = e0 + e0;  e1d = e1 + e1;  e0kd = e0k + e0k;  e1kd = e1k + e1k;
        e0q = e0d + e0d; e1q = e1d + e1d; e0kq = e0kd + e0kd; e1kq = e1kd + e1kd;

        // Approximate convergence gates (wave-uniform, NaN-safe).
        bool per1 = __builtin_fabsf(fc - fc_p1) <= TAU_CONV;
        bool per2 = __builtin_fabsf(fc - fc_p2) <= TAU_CONV;
        if (__all(per1)) { mode = 1; break; }
        if (__all(per2) && ((10 - c) & 1)) { mode = 2; break; }
        fc_p2 = fc_p1;
        fc_p1 = fc;

        if (c == 0) {
            // cold: 22 @ l4 + 4 @ l1  (residual ~ R17 cold: 6.4e-3)
            solve4(22, sx0, sx1, e0q, e1q, e0kq, e1kq, tw0, tw1, p, xt0, xt1);
            solve(1, xt0, xt1, e0, e1, e0k, e1k, p, xt0, xt1);
        } else {
            // warm: 10 @ l4 + 4 @ l1  (residual ~ R17 warm: 0.12)
            solve4(10, xt0, xt1, e0q, e1q, e0kq, e1kq, tw0, tw1, p, xt0, xt1);
            solve(1, xt0, xt1, e0, e1, e0k, e1k, p, xt0, xt1);
        }
    }

    if (c == 11) {   // natural exhaust: e-consts refreshed at the last state
        float sp = __builtin_fmaf(xt0, p.w0, __builtin_fmaf(xt1, p.w1, bp1));
        float tt = __builtin_fmaf(sp, sp, 1.0f);
        float rs = rsq_nr(tt);
        float fc = (0.5f * sp) * rs;
        e0 = __builtin_fmaf(fc, p.w0, p5r0);
        e1 = __builtin_fmaf(fc, p.w1, p5r1);
        e0k = e0 - k0;
        e1k = e1 - k1;
        e0d = e0 + e0;  e1d = e1 + e1;  e0kd = e0k + e0k;  e1kd = e1k + e1k;
        e0q = e0d + e0d; e1q = e1d + e1d; e0kq = e0kd + e0kd; e1kq = e1kd + e1kd;
    }

    // Final (differentiable) solve, three-speed with step-down tail
    // (l4 kink-amplitude excess damped by 0.9^4 then 0.95^8).
    float x0, x1;
    if (mode == 1) {
        // warm: 6 @ l4 + 4 @ l2 + 8 @ l1  (residual ~ R17 final-warm)
        solve4(6, xt0, xt1, e0q, e1q, e0kq, e1kq, tw0, tw1, p, x0, x1);
        solve2(2, x0, x1, e0d, e1d, e0kd, e1kd, p, x0, x1);
        solve(2, x0, x1, e0, e1, e0k, e1k, p, x0, x1);
    } else {
        // cold: 28 @ l4 + 4 @ l2 + 8 @ l1  (residual ~ R17 final-cold)
        solve4(28, sx0, sx1, e0q, e1q, e0kq, e1kq, tw0, tw1, p, x0, x1);
        solve2(2, x0, x1, e0d, e1d, e0kd, e1kd, p, x0, x1);
        solve(2, x0, x1, e0, e1, e0k, e1k, p, x0, x1);
    }

    out[i] = __builtin_fmaf(x0, p.w0, __builtin_fmaf(x1, p.w1, b));
}

extern "C" void kernel_launch(void* const* d_in, const int* in_sizes, int n_in,
                              void* d_out, int out_size, void* d_ws, size_t ws_size,
                              hipStream_t stream) {
    const float* X = (const float*)d_in[0];
    const float* w = (const float*)d_in[1];
    const float* b = (const float*)d_in[2];
    const float* v = (const float*)d_in[3];
    float* out = (float*)d_out;

    int B = in_sizes[0] / 2;   // X is [B, 2], 1 sample per thread
    int block = 256;
    int grid = (B + block - 1) / block;
    strategic_kernel<<<grid, block, 0, stream>>>(X, w, b, v, out, B);
}

// Round 13
// 79.145 us; speedup vs baseline: 7.7411x; 1.0052x over previous
//
#include <hip/hip_runtime.h>

// Problem: MyStrategicModel_35691178229867
// R21 == R18 verbatim (revert). R19/R20 Steffensen FAILED (absmax 3.75):
// the per1 gate's soundness rests on PLAIN-orbit stagnation (bounds the
// reference's remaining movement); a certified Aitken jump instead proves
// WE reached g's fixed point -- but samples whose plain orbit hasn't
// stagnated by round 10 have a truncated reference trajectory far from
// that FP => O(1) deviation. Third confirmation of the boundary:
// admissible transforms must track the reference TRAJECTORY, not its
// limit (R11: map perturbation; R19: trajectory acceleration).
// R18 ladder recap: 222 -> 213 (unpack) -> 148 (tau-gate) -> 139 (trunc)
// -> 128 (warm final) -> 102 (warm chain) -> 88 (lambda2) -> 79.6 (lambda4).
// Remaining levers are net-negative: warm-trim ~0 (gate fires later),
// final-trim <2us, lambda>4 breaks the R8 staleness scale. Holding here.
// Predict: bench ~79-82us, absmax exactly 0.03125.

#define XLO -10.0f
#define XHI 10.0f
#define TAU_CONV 4e-4f

__device__ __forceinline__ float clampx(float x) {
    return __builtin_amdgcn_fmed3f(x, XLO, XHI);   // v_med3_f32, x finite
}

__device__ __forceinline__ float rsq_nr(float t) {
    float y = __builtin_amdgcn_rsqf(t);
    float c = __builtin_fmaf(-0.5f * (t * y), y, 1.5f);
    return y * c;
}

struct P {
    float w0, w1, v0, v1, bm1, hw0, hw1, mvr;
};

// lambda=1 solve: blocks of 4 steps, gc refreshed per block (R8-proven).
__device__ __forceinline__ void solve(int nblocks, float sx0, float sx1,
                                      float e0, float e1, float e0k, float e1k,
                                      const P& p, float& ox0, float& ox1) {
    float x0 = sx0, x1 = sx1;
    for (int k = 0; k < nblocks; ++k) {
        float tau = __builtin_fmaf(x0, p.w0, __builtin_fmaf(x1, p.w1, p.bm1));
        float t2  = __builtin_fmaf(tau, tau, 1.0f);
        float rq  = __builtin_amdgcn_rsqf(t2);
        float gc  = tau * rq;
        float f0  = __builtin_fmaf(-gc, p.hw0, e0);    // no-kink branch const
        float f0k = __builtin_fmaf(-gc, p.hw0, e0k);   // kink branch const
        float f1  = __builtin_fmaf(-gc, p.hw1, e1);
        float f1k = __builtin_fmaf(-gc, p.hw1, e1k);
#pragma unroll
        for (int h = 0; h < 4; ++h) {
            float q  = __builtin_fmaf(x0, p.v0, __builtin_fmaf(x1, p.v1, p.mvr));
            float a0 = (q > 0.0f) ? f0k : f0;
            float a1 = (q > 0.0f) ? f1k : f1;
            x0 = clampx(__builtin_fmaf(0.95f, x0, a0));
            x1 = clampx(__builtin_fmaf(0.95f, x1, a1));
        }
    }
    ox0 = x0;
    ox1 = x1;
}

// lambda=2 solve: blocks of 2 steps, gc refreshed per block (R17-proven).
__device__ __forceinline__ void solve2(int nblocks, float sx0, float sx1,
                                       float e0d, float e1d, float e0kd, float e1kd,
                                       const P& p, float& ox0, float& ox1) {
    float x0 = sx0, x1 = sx1;
    for (int k = 0; k < nblocks; ++k) {
        float tau = __builtin_fmaf(x0, p.w0, __builtin_fmaf(x1, p.w1, p.bm1));
        float t2  = __builtin_fmaf(tau, tau, 1.0f);
        float rq  = __builtin_amdgcn_rsqf(t2);
        float gc  = tau * rq;
        float f0  = __builtin_fmaf(-gc, p.w0, e0d);    // 2*hw0 = w0
        float f0k = __builtin_fmaf(-gc, p.w0, e0kd);
        float f1  = __builtin_fmaf(-gc, p.w1, e1d);
        float f1k = __builtin_fmaf(-gc, p.w1, e1kd);
#pragma unroll
        for (int h = 0; h < 2; ++h) {
            float q  = __builtin_fmaf(x0, p.v0, __builtin_fmaf(x1, p.v1, p.mvr));
            float a0 = (q > 0.0f) ? f0k : f0;
            float a1 = (q > 0.0f) ? f1k : f1;
            x0 = clampx(__builtin_fmaf(0.90f, x0, a0));
            x1 = clampx(__builtin_fmaf(0.90f, x1, a1));
        }
    }
    ox0 = x0;
    ox1 = x1;
}

// lambda=4 solve: gc refreshed EVERY step (R18-proven; staleness window =
// 4 l1-units = R8 scale). Select-then-fold, 16 ops/step.
__device__ __forceinline__ void solve4(int nsteps, float sx0, float sx1,
                                       float e0q, float e1q, float e0kq, float e1kq,
                                       float tw0, float tw1,
                                       const P& p, float& ox0, float& ox1) {
    float x0 = sx0, x1 = sx1;
#pragma unroll 2
    for (int k = 0; k < nsteps; ++k) {
        float q    = __builtin_fmaf(x0, p.v0, __builtin_fmaf(x1, p.v1, p.mvr));
        float sel0 = (q > 0.0f) ? e0kq : e0q;
        float sel1 = (q > 0.0f) ? e1kq : e1q;
        float tau = __builtin_fmaf(x0, p.w0, __builtin_fmaf(x1, p.w1, p.bm1));
        float t2  = __builtin_fmaf(tau, tau, 1.0f);
        float rq  = __builtin_amdgcn_rsqf(t2);
        float gc  = tau * rq;
        float a0  = __builtin_fmaf(-gc, tw0, sel0);
        float a1  = __builtin_fmaf(-gc, tw1, sel1);
        x0 = clampx(__builtin_fmaf(0.80f, x0, a0));
        x1 = clampx(__builtin_fmaf(0.80f, x1, a1));
    }
    ox0 = x0;
    ox1 = x1;
}

__global__ __launch_bounds__(256, 8)
void strategic_kernel(const float* __restrict__ X,
                      const float* __restrict__ wp,
                      const float* __restrict__ bp,
                      const float* __restrict__ vp,
                      float* __restrict__ out, int B) {
    int i = blockIdx.x * blockDim.x + threadIdx.x;
    if (i >= B) return;

    const float w0 = wp[0], w1 = wp[1], b = bp[0], v0 = vp[0], v1 = vp[1];

    P p;
    p.w0 = w0; p.w1 = w1; p.v0 = v0; p.v1 = v1;
    p.bm1 = b - 1.0f;
    p.hw0 = 0.5f * w0; p.hw1 = 0.5f * w1;
    const float tw0 = w0 + w0, tw1 = w1 + w1;        // lambda4 * hw = 2w
    const float bp1 = b + 1.0f;
    const float k0 = 0.475f * v0, k1 = 0.475f * v1;  // COST*(1-EPS)*v

    float2 r = reinterpret_cast<const float2*>(X)[i];
    const float r0 = r.x, r1 = r.y;

    const float sx0 = clampx(r0), sx1 = clampx(r1);  // inner-solve start
    p.mvr = -(__builtin_fmaf(r1, v1, r0 * v0));
    const float p5r0 = 0.05f * r0, p5r1 = 0.05f * r1;
    float xt0 = r0, xt1 = r1;                        // CCP state

    // fc history; NaN init => gates stay closed for first rounds
    float fc_p1 = __builtin_nanf(""), fc_p2 = __builtin_nanf("");
    float e0, e1, e0k, e1k;
    float e0d, e1d, e0kd, e1kd;      // x2 (lambda2)
    float e0q, e1q, e0kq, e1kq;      // x4 (lambda4)

    int mode = 0;   // 0 = exhaust/none, 1 = per1 break, 2 = per2 break
    int c = 0;
    for (; c < 11; ++c) {
        // fder at xt (NR-refined rsq; 11 calls, cheap)
        float sp = __builtin_fmaf(xt0, p.w0, __builtin_fmaf(xt1, p.w1, bp1));
        float tt = __builtin_fmaf(sp, sp, 1.0f);
        float rs = rsq_nr(tt);
        float fc = (0.5f * sp) * rs;
        e0 = __builtin_fmaf(fc, p.w0, p5r0);
        e1 = __builtin_fmaf(fc, p.w1, p5r1);
        e0k = e0 - k0;
        e1k = e1 - k1;
        e0d = e0 + e0;  e1d = e1 + e1;  e0kd = e0k + e0k;  e1kd = e1k + e1k;
        e0q = e0d + e0d; e1q = e1d + e1d; e0kq = e0kd + e0kd; e1kq = e1kd + e1kd;

        // Approximate convergence gates (wave-uniform, NaN-safe).
        bool per1 = __builtin_fabsf(fc - fc_p1) <= TAU_CONV;
        bool per2 = __builtin_fabsf(fc - fc_p2) <= TAU_CONV;
        if (__all(per1)) { mode = 1; break; }
        if (__all(per2) && ((10 - c) & 1)) { mode = 2; break; }
        fc_p2 = fc_p1;
        fc_p1 = fc;

        if (c == 0) {
            // cold: 22 @ l4 + 4 @ l1  (residual ~ R17 cold: 6.4e-3)
            solve4(22, sx0, sx1, e0q, e1q, e0kq, e1kq, tw0, tw1, p, xt0, xt1);
            solve(1, xt0, xt1, e0, e1, e0k, e1k, p, xt0, xt1);
        } else {
            // warm: 10 @ l4 + 4 @ l1  (residual ~ R17 warm: 0.12)
            solve4(10, xt0, xt1, e0q, e1q, e0kq, e1kq, tw0, tw1, p, xt0, xt1);
            solve(1, xt0, xt1, e0, e1, e0k, e1k, p, xt0, xt1);
        }
    }

    if (c == 11) {   // natural exhaust: e-consts refreshed at the last state
        float sp = __builtin_fmaf(xt0, p.w0, __builtin_fmaf(xt1, p.w1, bp1));
        float tt = __builtin_fmaf(sp, sp, 1.0f);
        float rs = rsq_nr(tt);
        float fc = (0.5f * sp) * rs;
        e0 = __builtin_fmaf(fc, p.w0, p5r0);
        e1 = __builtin_fmaf(fc, p.w1, p5r1);
        e0k = e0 - k0;
        e1k = e1 - k1;
        e0d = e0 + e0;  e1d = e1 + e1;  e0kd = e0k + e0k;  e1kd = e1k + e1k;
        e0q = e0d + e0d; e1q = e1d + e1d; e0kq = e0kd + e0kd; e1kq = e1kd + e1kd;
    }

    // Final (differentiable) solve, three-speed with step-down tail
    // (l4 kink-amplitude excess damped by l2 then l1 phases).
    float x0, x1;
    if (mode == 1) {
        // warm: 6 @ l4 + 4 @ l2 + 8 @ l1  (residual ~ R17 final-warm)
        solve4(6, xt0, xt1, e0q, e1q, e0kq, e1kq, tw0, tw1, p, x0, x1);
        solve2(2, x0, x1, e0d, e1d, e0kd, e1kd, p, x0, x1);
        solve(2, x0, x1, e0, e1, e0k, e1k, p, x0, x1);
    } else {
        // cold: 28 @ l4 + 4 @ l2 + 8 @ l1  (residual ~ R17 final-cold)
        solve4(28, sx0, sx1, e0q, e1q, e0kq, e1kq, tw0, tw1, p, x0, x1);
        solve2(2, x0, x1, e0d, e1d, e0kd, e1kd, p, x0, x1);
        solve(2, x0, x1, e0, e1, e0k, e1k, p, x0, x1);
    }

    out[i] = __builtin_fmaf(x0, p.w0, __builtin_fmaf(x1, p.w1, b));
}

extern "C" void kernel_launch(void* const* d_in, const int* in_sizes, int n_in,
                              void* d_out, int out_size, void* d_ws, size_t ws_size,
                              hipStream_t stream) {
    const float* X = (const float*)d_in[0];
    const float* w = (const float*)d_in[1];
    const float* b = (const float*)d_in[2];
    const float* v = (const float*)d_in[3];
    float* out = (float*)d_out;

    int B = in_sizes[0] / 2;   // X is [B, 2], 1 sample per thread
    int block = 256;
    int grid = (B + block - 1) / block;
    strategic_kernel<<<grid, block, 0, stream>>>(X, w, b, v, out, B);
}